// Round 8
// baseline (55.179 us; speedup 1.0000x reference)
//
#include <hip/hip_runtime.h>

#define EPSF 1e-6f
#define L2E  1.44269504088896340736f   // log2(e)

using bf16x8 = __attribute__((ext_vector_type(8))) short;  // 8 bf16 (4 VGPRs)
using f32x16 = __attribute__((ext_vector_type(16))) float;

constexpr int NT    = 256;
constexpr int JC    = 256;               // q columns per block
constexpr int NJC   = 8192 / JC;         // 32 chunks
constexpr int RPAN  = 128;               // z rows per block (4 waves x 32)
constexpr int NRP   = 16384 / RPAN;      // 128 row panels
constexpr int NB    = NRP * NJC;         // 4096 blocks
constexpr int JT    = JC / 32;           // 8 j-tiles per chunk
constexpr int RSTR  = 24;                // padded row stride in shorts (48B, 16B-aligned)

// RNE float -> bf16 (as short), and back
__device__ __forceinline__ short f2bf(float f) {
    union { float f; unsigned u; } c{f};
    return (short)((c.u + 0x7fffu + ((c.u >> 16) & 1u)) >> 16);
}
__device__ __forceinline__ float bf2f(short s) {
    union { unsigned u; float f; } c{((unsigned)(unsigned short)s) << 16};
    return c.f;
}

// ---------------------------------------------------------------------------
__device__ __forceinline__ float block_reduce_sum(float v) {
#pragma unroll
    for (int off = 32; off > 0; off >>= 1) v += __shfl_down(v, off, 64);
    __shared__ float parts[4];
    const int t = threadIdx.x;
    if ((t & 63) == 0) parts[t >> 6] = v;
    __syncthreads();
    float r = 0.f;
    if (t == 0) r = parts[0] + parts[1] + parts[2] + parts[3];
    return r;
}

// ---------------------------------------------------------------------------
// Dense: K=10 augmented 32x32x16 MFMA emits d2 = L2E^2*dist^2 directly.
//   A row i = [zh_0..zh_7, zn_i, 1, 0...]   zh = bf16(L2E*(z+eps)), zn=|zh|^2
//   B col j = [-2qh_0..-2qh_7, 1, qn_j, 0...] qh = bf16(L2E*q),  qn=|qh|^2
//   term = ed_j * 2^(-sqrt(D));  weight exp(gamma_i) at the end.
// Pipelined: all 8 B-frags preloaded to VGPR; MFMA(jt+1) issued before
// epilogue(jt) so LDS/MFMA latency is never exposed.
// ---------------------------------------------------------------------------
__global__ __launch_bounds__(NT) void fused_kernel(
    const float* __restrict__ z, const float* __restrict__ q,
    const float* __restrict__ gamma, const float* __restrict__ delta,
    const float* __restrict__ w, const int* __restrict__ si,
    const int* __restrict__ sj, int nnz, float* __restrict__ partial)
{
    __shared__ short sza[RPAN * RSTR];   // 6KB  A-side rows
    __shared__ float seg[RPAN];          // 512B exp(gamma)
    __shared__ short sqb[JC * RSTR];     // 12KB B-side cols
    __shared__ float sed[JC];            // 1KB  exp(delta - eps)

    const int t    = threadIdx.x;
    const int id   = blockIdx.x;
    const int jc   = id & (NJC - 1);
    const int rpan = id >> 5;            // id / NJC
    const int c0   = jc * JC;

    // ---- stage z-panel (128 rows; threads 0..127) ----
    if (t < RPAN) {
        const int row = rpan * RPAN + t;
        const float4 a = *(const float4*)(z + (size_t)row * 8);
        const float4 b = *(const float4*)(z + (size_t)row * 8 + 4);
        const float h[8] = {L2E * (a.x + EPSF), L2E * (a.y + EPSF),
                            L2E * (a.z + EPSF), L2E * (a.w + EPSF),
                            L2E * (b.x + EPSF), L2E * (b.y + EPSF),
                            L2E * (b.z + EPSF), L2E * (b.w + EPSF)};
        float zn = 0.f;
#pragma unroll
        for (int d = 0; d < 8; ++d) {
            const short s = f2bf(h[d]);
            sza[t * RSTR + d] = s;
            const float r = bf2f(s);
            zn = fmaf(r, r, zn);
        }
        sza[t * RSTR + 8] = f2bf(zn);
        sza[t * RSTR + 9] = (short)0x3F80;   // 1.0 bf16
#pragma unroll
        for (int d = 10; d < 16; ++d) sza[t * RSTR + d] = 0;
        seg[t] = __expf(gamma[row]);
    }

    // ---- stage q-chunk (256 cols; one per thread) ----
    {
        const int C = c0 + t;
        const float4 a = *(const float4*)(q + (size_t)C * 8);
        const float4 b = *(const float4*)(q + (size_t)C * 8 + 4);
        const float h[8] = {L2E * a.x, L2E * a.y, L2E * a.z, L2E * a.w,
                            L2E * b.x, L2E * b.y, L2E * b.z, L2E * b.w};
        float qn = 0.f;
#pragma unroll
        for (int d = 0; d < 8; ++d) {
            const short s = f2bf(h[d]);
            const float r = bf2f(s);
            qn = fmaf(r, r, qn);
            sqb[t * RSTR + d] = f2bf(-2.f * r);  // exact: -2x is exponent shift
        }
        sqb[t * RSTR + 8] = (short)0x3F80;       // 1.0 bf16
        sqb[t * RSTR + 9] = f2bf(qn);
#pragma unroll
        for (int d = 10; d < 16; ++d) sqb[t * RSTR + d] = 0;
        sed[t] = __expf(delta[C] - EPSF);
    }

    // ---- sparse slice (exact fp32; nothing fat live across it) ----
    float sacc = 0.f;
    for (int k = id * NT + t; k < nnz; k += NB * NT) {
        const int i = si[k];
        const int j = sj[k];
        const float4 a = *(const float4*)(z + (size_t)i * 8);
        const float4 b = *(const float4*)(z + (size_t)i * 8 + 4);
        const float4 c = *(const float4*)(q + (size_t)j * 8);
        const float4 d = *(const float4*)(q + (size_t)j * 8 + 4);
        const float d0 = a.x - c.x + EPSF, d1 = a.y - c.y + EPSF;
        const float d2 = a.z - c.z + EPSF, d3 = a.w - c.w + EPSF;
        const float d4 = b.x - d.x + EPSF, d5 = b.y - d.y + EPSF;
        const float d6 = b.z - d.z + EPSF, d7 = b.w - d.w + EPSF;
        float s2 = d0 * d0;
        s2 = fmaf(d1, d1, s2); s2 = fmaf(d2, d2, s2); s2 = fmaf(d3, d3, s2);
        s2 = fmaf(d4, d4, s2); s2 = fmaf(d5, d5, s2); s2 = fmaf(d6, d6, s2);
        s2 = fmaf(d7, d7, s2);
        const float dist = __builtin_amdgcn_sqrtf(s2);
        sacc = fmaf(w[k], gamma[i] + delta[j] - dist, sacc);
    }
    __syncthreads();

    // ---- per-wave MFMA over 8 j-tiles of a 32-row band ----
    const int wv   = t >> 6;
    const int lane = t & 63;
    const int li   = lane & 31;
    const int half = lane >> 5;

    const bf16x8 afrag = *(const bf16x8*)&sza[(wv * 32 + li) * RSTR + half * 8];

    // preload ALL B-frags + ed values (one lgkm drain total)
    bf16x8 bf[JT];
    float  edv[JT];
#pragma unroll
    for (int jt = 0; jt < JT; ++jt) {
        bf[jt]  = *(const bf16x8*)&sqb[(jt * 32 + li) * RSTR + half * 8];
        edv[jt] = sed[jt * 32 + li];
    }

    float acc[16];
#pragma unroll
    for (int r = 0; r < 16; ++r) acc[r] = 0.f;

    // software-pipelined: MFMA for jt+1 issued before epilogue of jt
    f32x16 sc = __builtin_amdgcn_mfma_f32_32x32x16_bf16(
        afrag, bf[0], (f32x16)(0.f), 0, 0, 0);
#pragma unroll
    for (int jt = 0; jt < JT; ++jt) {
        f32x16 sn;
        if (jt + 1 < JT)
            sn = __builtin_amdgcn_mfma_f32_32x32x16_bf16(
                afrag, bf[jt + 1], (f32x16)(0.f), 0, 0, 0);
        const float ed_l = edv[jt];
#pragma unroll
        for (int r = 0; r < 16; ++r) {
            const float d2 = fmaxf(sc[r], 0.f);
            const float st = __builtin_amdgcn_sqrtf(d2);   // = L2E * dist
            acc[r] = fmaf(ed_l, __builtin_amdgcn_exp2f(-st), acc[r]);
        }
        if (jt + 1 < JT) sc = sn;
    }

    // weight by exp(gamma_row); row = wv*32 + 4*half + (reg&3) + 8*(reg>>2)
    float vv = 0.f;
#pragma unroll
    for (int r4 = 0; r4 < 4; ++r4)
#pragma unroll
        for (int r0 = 0; r0 < 4; ++r0)
            vv = fmaf(seg[wv * 32 + half * 4 + r0 + 8 * r4], acc[r4 * 4 + r0], vv);

    const float v = block_reduce_sum(sacc - vv);
    if (t == 0) partial[id] = v;
}

// ---------------------------------------------------------------------------
__global__ __launch_bounds__(256) void reduce_kernel(
    const float* __restrict__ partial, int n, float* __restrict__ out)
{
    float v = 0.f;
    for (int k = threadIdx.x; k < n; k += 256) v += partial[k];
    v = block_reduce_sum(v);
    if (threadIdx.x == 0) out[0] = v;
}

// ---------------------------------------------------------------------------
extern "C" void kernel_launch(void* const* d_in, const int* in_sizes, int n_in,
                              void* d_out, int out_size, void* d_ws, size_t ws_size,
                              hipStream_t stream) {
    const float* z     = (const float*)d_in[0];   // [16384, 8]
    const float* q     = (const float*)d_in[1];   // [8192, 8]
    const float* gamma = (const float*)d_in[2];   // [16384]
    const float* delta = (const float*)d_in[3];   // [8192]
    const float* w     = (const float*)d_in[4];   // [nnz]
    const int*   si    = (const int*)d_in[5];     // [nnz]
    const int*   sj    = (const int*)d_in[6];     // [nnz]
    const int    nnz   = in_sizes[4];

    float* out = (float*)d_out;
    float* ws  = (float*)d_ws;

    fused_kernel<<<NB, NT, 0, stream>>>(z, q, gamma, delta, w, si, sj, nnz, ws);
    reduce_kernel<<<1, 256, 0, stream>>>(ws, NB, out);
}